// Round 8
// baseline (43.878 us; speedup 1.0000x reference)
//
#include <hip/hip_runtime.h>

// Fixed sizes
#define G_    32
#define O_    16
#define OUTD  128
#define DS_   64      // scalar half / SDIM
#define VC    48      // V*3
#define M_    2048    // rows per graph
#define ROWS  128     // rows per chunk block
#define CPG   16      // chunks per graph (2048/128)
#define XP    136     // xT / cT pitch in bf16 elems (rows 16B-aligned: 272B)
#define XPD   68      // pitch in dwords
#define WVP   72      // wv_s pitch in bf16
#define YLP   132     // y_lds pitch in f32 (mult of 4 for float4 reads)

typedef __attribute__((ext_vector_type(8))) short short8;
typedef __attribute__((ext_vector_type(4))) float f32x4;

__device__ __forceinline__ unsigned short f2bf(float f) {
  unsigned u = __float_as_uint(f);
  return (unsigned short)((u + 0x7FFFu + ((u >> 16) & 1u)) >> 16);
}
__device__ __forceinline__ float bf2f(short v) {
  return __uint_as_float(((unsigned)(unsigned short)v) << 16);
}

// ---------------------------------------------------------------------------
// K0: transpose+convert x -> bf16 xTg (once), plus per-chunk column sums.
//   xTg[g][chunk] is a contiguous [k=128][m=128] bf16 block (32 KB).
//   ysum_part[g*16+chunk][k] = sum_m bf16(x)[m][k]  (it-0 y is rank-1).
// ---------------------------------------------------------------------------
__global__ __launch_bounds__(256) void stage_x(
    const float* __restrict__ x, short* __restrict__ xTg,
    float* __restrict__ ysum_part)
{
  const int blk = blockIdx.x;
  const int t = threadIdx.x;
  __shared__ short xT[128 * XP];

  const float* xg = x + (size_t)blk * (ROWS * OUTD);
  {
    const int rg = t >> 2, qc = t & 3;
    const float4* r0q = (const float4*)(xg + (size_t)(2 * rg) * OUTD + qc * 32);
    const float4* r1q = (const float4*)(xg + (size_t)(2 * rg + 1) * OUTD + qc * 32);
    float4 a0 = r0q[0], a1 = r0q[1], a2 = r0q[2], a3 = r0q[3],
           a4 = r0q[4], a5 = r0q[5], a6 = r0q[6], a7 = r0q[7];
    float4 b0 = r1q[0], b1 = r1q[1], b2 = r1q[2], b3 = r1q[3],
           b4 = r1q[4], b5 = r1q[5], b6 = r1q[6], b7 = r1q[7];
    unsigned* xTd = (unsigned*)xT;
    const int cb = qc * 32;
#define STAGE4(S, A, B)                                                        \
    xTd[(cb + S*4 + 0) * XPD + rg] = (unsigned)f2bf(A.x) | ((unsigned)f2bf(B.x) << 16); \
    xTd[(cb + S*4 + 1) * XPD + rg] = (unsigned)f2bf(A.y) | ((unsigned)f2bf(B.y) << 16); \
    xTd[(cb + S*4 + 2) * XPD + rg] = (unsigned)f2bf(A.z) | ((unsigned)f2bf(B.z) << 16); \
    xTd[(cb + S*4 + 3) * XPD + rg] = (unsigned)f2bf(A.w) | ((unsigned)f2bf(B.w) << 16);
    STAGE4(0, a0, b0) STAGE4(1, a1, b1) STAGE4(2, a2, b2) STAGE4(3, a3, b3)
    STAGE4(4, a4, b4) STAGE4(5, a5, b5) STAGE4(6, a6, b6) STAGE4(7, a7, b7)
#undef STAGE4
  }
  __syncthreads();

  // writeout: xT LDS -> xTg global, contiguous [k][128] bf16
  {
    short8* dst = (short8*)(xTg + (size_t)blk * (128 * 128));
#pragma unroll
    for (int i = 0; i < 8; ++i) {
      int c = i * 256 + t;
      dst[c] = *(const short8*)&xT[(c >> 4) * XP + (c & 15) * 8];
    }
  }
  // column sums: k = t>>1, halves combined via shfl
  {
    const int k = t >> 1, half = t & 1;
    float s = 0.f;
#pragma unroll
    for (int j = 0; j < 8; ++j) {
      short8 v = *(const short8*)&xT[k * XP + half * 64 + j * 8];
#pragma unroll
      for (int e = 0; e < 8; ++e) s += bf2f(v[e]);
    }
    s += __shfl_xor(s, 1);
    if (half == 0) ysum_part[(size_t)blk * 128 + k] = s;
  }
}

// ---------------------------------------------------------------------------
// capsA_t<LAST>: stage bf16 xTg -> LDS, GEMM1 logits + softmax -> cT,
//   GEMM2 -> y_part[g][chunk][o][k].  LAST: cp + routed partials.
//   Distinct template instantiations give distinct rocprof names.
// ---------------------------------------------------------------------------
template<int LAST>
__global__ __launch_bounds__(256) void capsA_t(
    const short* __restrict__ xTg, const float* __restrict__ xv,
    const float* __restrict__ wvacc, float* __restrict__ y_part,
    float* __restrict__ routed_part)
{
  const int blk = blockIdx.x, g = blk >> 4, chunk = blk & 15;
  const int t = threadIdx.x, lane = t & 63, w = t >> 6;

  __shared__ short xT[128 * XP];      // 34816 B
  __shared__ short cT[O_ * XP];       // 4352 B
  __shared__ short wv_s[O_ * WVP];    // 2304 B
  __shared__ float cp_s[16][17];      // 1088 B
  __shared__ float xv_s[16 * VC];     // 3072 B
  __shared__ float y_lds[16 * YLP];   // 8448 B

  // ---- stage xTg -> xT (pure reg copy, 16B/lane) ----
  {
    const short8* src = (const short8*)(xTg + (size_t)blk * (128 * 128));
#pragma unroll
    for (int i = 0; i < 8; ++i) {
      int c = i * 256 + t;
      *(short8*)&xT[(c >> 4) * XP + (c & 15) * 8] = src[c];
    }
  }
  {
    const float* wvg = wvacc + (size_t)g * O_ * DS_;
    for (int i = t; i < O_ * DS_; i += 256) {
      int o = i >> 6, k = i & 63;
      wv_s[o * WVP + k] = (short)f2bf(wvg[i]);
    }
  }
  if (LAST) {
    const float* xvg = xv + (size_t)(g * 256 + chunk * 16) * VC;
    for (int i = t; i < 16 * VC; i += 256) xv_s[i] = xvg[i];
  }
  __syncthreads();

  // ---- GEMM1 + softmax -> cT (+ registers for cp) ----
  {
    const int mrow = lane & 15, gq = lane >> 4;
    float c_fA[4], c_fB[4];
#define LOGIT_TILE(NT2, CF)                                                    \
    {                                                                          \
      const int nt = 2 * w + NT2;                                              \
      const int mcol = nt * 16 + mrow;                                         \
      f32x4 acc = {0.f, 0.f, 0.f, 0.f};                                        \
      _Pragma("unroll")                                                        \
      for (int ks = 0; ks < 2; ++ks) {                                         \
        short8 af = *(const short8*)&wv_s[mrow * WVP + ks * 32 + gq * 8];      \
        short8 bf;                                                             \
        _Pragma("unroll")                                                      \
        for (int e = 0; e < 8; ++e)                                            \
          bf[e] = xT[(ks * 32 + gq * 8 + e) * XP + mcol];                      \
        acc = __builtin_amdgcn_mfma_f32_16x16x32_bf16(af, bf, acc, 0, 0, 0);   \
      }                                                                        \
      float mx = fmaxf(fmaxf(acc[0], acc[1]), fmaxf(acc[2], acc[3]));          \
      mx = fmaxf(mx, __shfl_xor(mx, 16));                                      \
      mx = fmaxf(mx, __shfl_xor(mx, 32));                                      \
      float e0 = __expf(acc[0] - mx), e1 = __expf(acc[1] - mx);                \
      float e2 = __expf(acc[2] - mx), e3 = __expf(acc[3] - mx);                \
      float sm = e0 + e1 + e2 + e3;                                            \
      sm += __shfl_xor(sm, 16);                                                \
      sm += __shfl_xor(sm, 32);                                                \
      float inv = 1.f / sm;                                                    \
      CF[0] = e0 * inv; CF[1] = e1 * inv; CF[2] = e2 * inv; CF[3] = e3 * inv;  \
      cT[(gq * 4 + 0) * XP + mcol] = (short)f2bf(CF[0]);                       \
      cT[(gq * 4 + 1) * XP + mcol] = (short)f2bf(CF[1]);                       \
      cT[(gq * 4 + 2) * XP + mcol] = (short)f2bf(CF[2]);                       \
      cT[(gq * 4 + 3) * XP + mcol] = (short)f2bf(CF[3]);                       \
    }
    LOGIT_TILE(0, c_fA)
    LOGIT_TILE(1, c_fB)
#undef LOGIT_TILE

    if (LAST) {
#define CP_TILE(NT2, CF)                                                       \
      {                                                                        \
        const int nt = 2 * w + NT2;                                            \
        _Pragma("unroll")                                                      \
        for (int r = 0; r < 4; ++r) {                                          \
          float v = CF[r];                                                     \
          v += __shfl_xor(v, 1); v += __shfl_xor(v, 2); v += __shfl_xor(v, 4); \
          if ((lane & 7) == 0)                                                 \
            cp_s[nt * 2 + ((lane >> 3) & 1)][gq * 4 + r] = v;                  \
        }                                                                      \
      }
      CP_TILE(0, c_fA)
      CP_TILE(1, c_fB)
#undef CP_TILE
    }
  }
  __syncthreads();

  // ---- GEMM2: y[k][o] = sum_m xT[k][m]*c[m][o] -> y_lds[o][k] ----
  {
    const int oc = lane & 15, gq = lane >> 4;
    f32x4 y0 = {0.f, 0.f, 0.f, 0.f}, y1 = {0.f, 0.f, 0.f, 0.f};
#pragma unroll
    for (int ks = 0; ks < 4; ++ks) {
      short8 bf = *(const short8*)&cT[oc * XP + ks * 32 + gq * 8];
      short8 a0 = *(const short8*)&xT[((2 * w + 0) * 16 + oc) * XP + ks * 32 + gq * 8];
      short8 a1 = *(const short8*)&xT[((2 * w + 1) * 16 + oc) * XP + ks * 32 + gq * 8];
      y0 = __builtin_amdgcn_mfma_f32_16x16x32_bf16(a0, bf, y0, 0, 0, 0);
      y1 = __builtin_amdgcn_mfma_f32_16x16x32_bf16(a1, bf, y1, 0, 0, 0);
    }
#pragma unroll
    for (int r = 0; r < 4; ++r) {
      y_lds[oc * YLP + (2 * w + 0) * 16 + gq * 4 + r] = y0[r];
      y_lds[oc * YLP + (2 * w + 1) * 16 + gq * 4 + r] = y1[r];
    }
  }
  __syncthreads();
  // coalesced writeout in [o][k] layout
  {
    float* yp = y_part + (size_t)(g * CPG + chunk) * 2048;
    const int oo = t >> 4, k8 = (t & 15) * 8;
    float4 q0 = *(const float4*)&y_lds[oo * YLP + k8];
    float4 q1 = *(const float4*)&y_lds[oo * YLP + k8 + 4];
    *(float4*)&yp[t * 8] = q0;
    *(float4*)&yp[t * 8 + 4] = q1;
  }

  // ---- routed partials (last): rp[o][j] = sum_{16 nodes} cp*xv ----
  if (LAST) {
    float* rp = routed_part + (size_t)(g * CPG + chunk) * 768;
#pragma unroll
    for (int e = 0; e < 3; ++e) {
      int idx = t + 256 * e;
      int o = idx / VC, j = idx % VC;
      float acc = 0.f;
#pragma unroll
      for (int n = 0; n < 16; ++n) acc += cp_s[n][o] * xv_s[n * VC + j];
      rp[idx] = acc;
    }
  }
}

// ---------------------------------------------------------------------------
// capsB_t<FIRST,LAST>: block (g, osub) handles o = 2*osub + {0,1}.
//   FIRST: y = colsum/16 (rank-1, from ysum_part);  else: reduce y_part.
//   s = y@W + bias; v = squash(s); !LAST: wvacc (=|+=); LAST: caps + vecs.
// ---------------------------------------------------------------------------
template<int FIRST, int LAST>
__global__ __launch_bounds__(256) void capsB_t(
    const float* __restrict__ y_part, const float* __restrict__ ysum_part,
    const float* __restrict__ Ws, const float* __restrict__ Wv,
    const float* __restrict__ bias, float* __restrict__ wvacc,
    float* __restrict__ caps, const float* __restrict__ routed_part,
    float* __restrict__ vecs)
{
  const int b = blockIdx.x, g = b >> 3, osub = b & 7, t = threadIdx.x;
  __shared__ float y_s[2][128];
  __shared__ float v_s[2][64];
  __shared__ float pn_s[4];

  if (FIRST) {
    if (t < 128) {
      float s = 0.f;
#pragma unroll
      for (int ch = 0; ch < CPG; ++ch)
        s += ysum_part[(size_t)(g * CPG + ch) * 128 + t];
      s *= 0.0625f;
      y_s[0][t] = s;
      y_s[1][t] = s;
    }
  } else {
    const int o2 = t >> 7, k = t & 127;
    const float* yp = y_part + (size_t)g * CPG * 2048 + (osub * 2 + o2) * 128 + k;
    float s = 0.f;
#pragma unroll
    for (int ch = 0; ch < CPG; ++ch) s += yp[ch * 2048];
    y_s[o2][k] = s;
  }
  __syncthreads();

  const int ol = t >> 7, d = t & 127, o = osub * 2 + ol;
  const float* W = (d < 64) ? (Ws + (size_t)o * 64 * 64 + d)
                            : (Wv + (size_t)o * 64 * 64 + (d - 64));
  const int kbase = (d < 64) ? 0 : 64;
  float s = 0.f;
#pragma unroll
  for (int k = 0; k < 64; ++k) s += y_s[ol][kbase + k] * W[k * 64];
  s += bias[o * OUTD + d];

  float pn = s * s;
#pragma unroll
  for (int m = 1; m < 64; m <<= 1) pn += __shfl_xor(pn, m);
  if ((t & 63) == 0) pn_s[t >> 6] = pn;
  __syncthreads();
  float sn = pn_s[ol * 2] + pn_s[ol * 2 + 1];
  float f = sn / ((1.f + sn) * (sqrtf(sn) + 1e-8f));
  float v = f * s;
  if (d < 64) v_s[ol][d] = v;
  if (LAST) caps[((size_t)g * O_ + o) * OUTD + d] = v;
  __syncthreads();

  if (!LAST) {
    if (t < 128) {
      int ol2 = t >> 6, k = t & 63, o2 = osub * 2 + ol2;
      const float* Wr = Ws + ((size_t)o2 * 64 + k) * 64;
      float acc = 0.f;
#pragma unroll
      for (int ss = 0; ss < 64; ss += 4) {
        float4 wq = *(const float4*)(Wr + ss);
        float4 vq = *(const float4*)&v_s[ol2][ss];
        acc += wq.x * vq.x + wq.y * vq.y + wq.z * vq.z + wq.w * vq.w;
      }
      float* wa = wvacc + ((size_t)g * O_ + o2) * 64 + k;
      *wa = (FIRST ? 0.f : *wa) + acc;
    }
  } else {
    if (t < 96) {
      int idx = osub * 96 + t;
      const float* rp = routed_part + (size_t)g * CPG * 768 + idx;
      float s2 = 0.f;
#pragma unroll
      for (int ch = 0; ch < CPG; ++ch) s2 += rp[ch * 768];
      vecs[(size_t)g * 768 + idx] = s2;
    }
  }
}

// ---------------------------------------------------------------------------
extern "C" void kernel_launch(void* const* d_in, const int* in_sizes, int n_in,
                              void* d_out, int out_size, void* d_ws, size_t ws_size,
                              hipStream_t stream)
{
  const float* x    = (const float*)d_in[0];
  const float* xv   = (const float*)d_in[1];
  const float* Ws   = (const float*)d_in[2];
  const float* Wv   = (const float*)d_in[3];
  const float* bias = (const float*)d_in[4];

  float* out  = (float*)d_out;
  float* caps = out;                           // (32,16,128)
  float* vecs = out + (size_t)G_ * O_ * OUTD;  // (32,16,16,3)

  // ws layout (floats):
  //   wvacc 32768 | y_part 1048576 | routed_part 393216 | ysum_part 65536
  //   | xTg 4194304 (as bf16: 8388608 elems)
  float* ws          = (float*)d_ws;
  float* wvacc       = ws;
  float* y_part      = ws + (size_t)G_ * O_ * DS_;
  float* routed_part = y_part + (size_t)G_ * CPG * 128 * 16;
  float* ysum_part   = routed_part + (size_t)G_ * CPG * 768;
  short* xTg         = (short*)(ysum_part + (size_t)G_ * CPG * 128);

  dim3 blk(256), grdA(G_ * CPG), grdB(G_ * 8);

  // it 0: stage x once; y is rank-1 (c uniform) -> colsum path in capsB
  stage_x<<<grdA, blk, 0, stream>>>(x, xTg, ysum_part);
  capsB_t<1, 0><<<grdB, blk, 0, stream>>>(y_part, ysum_part, Ws, Wv, bias,
                                          wvacc, caps, routed_part, vecs);
  // it 1
  capsA_t<0><<<grdA, blk, 0, stream>>>(xTg, xv, wvacc, y_part, routed_part);
  capsB_t<0, 0><<<grdB, blk, 0, stream>>>(y_part, ysum_part, Ws, Wv, bias,
                                          wvacc, caps, routed_part, vecs);
  // it 2 (final)
  capsA_t<1><<<grdA, blk, 0, stream>>>(xTg, xv, wvacc, y_part, routed_part);
  capsB_t<0, 1><<<grdB, blk, 0, stream>>>(y_part, ysum_part, Ws, Wv, bias,
                                          wvacc, caps, routed_part, vecs);
}